// Round 1
// baseline (242.232 us; speedup 1.0000x reference)
//
#include <hip/hip_runtime.h>
#include <math.h>

#define B_  2
#define DM  64
#define DI  128
#define Nn  16
#define Rr  4
#define KD  4      // directions actually used (k_sel only references 0..3)
#define KT  8      // directions present in the inputs
#define LL  4096
#define NC  64     // scan chunks per (b,k)
#define CS  64     // LL/NC

__device__ __forceinline__ float sigmoidf_(float x){ return 1.f/(1.f+__expf(-x)); }
__device__ __forceinline__ float siluf_(float x){ return x*sigmoidf_(x); }
__device__ __forceinline__ float softplusf_(float x){
  return fmaxf(x,0.f) + log1pf(__expf(-fabsf(x)));
}

// ---------------------------------------------------------------- K1: reverse3d + in_proj
// xz[b,l,:] = reverse3d(x)[b,l,:] @ W^T ; xin = xz[:,:,:128], z = xz[:,:,128:]
__global__ __launch_bounds__(256) void k1_inproj(
    const float* __restrict__ x, const float* __restrict__ W,
    float* __restrict__ xin, float* __restrict__ z)
{
  const int blk = blockIdx.x;             // B_*LL/16 = 512
  const int b  = blk / (LL/16);
  const int l0 = (blk % (LL/16)) * 16;
  const int t  = threadIdx.x;
  __shared__ float xs[16][64];
  for (int e = t; e < 16*64; e += 256){
    int j = e >> 6, c = e & 63;
    int l = l0 + j;
    int par = (l + b) & 1;                // reverse3d parity
    xs[j][c] = x[(b*LL + l)*DM + (par ? (63-c) : c)];
  }
  __syncthreads();
  float4 w[16];
  const float4* W4 = (const float4*)(W + t*64);
  #pragma unroll
  for (int i=0;i<16;i++) w[i] = W4[i];
  float acc[16];
  #pragma unroll
  for (int j=0;j<16;j++) acc[j] = 0.f;
  #pragma unroll
  for (int i=0;i<16;i++){
    #pragma unroll
    for (int j=0;j<16;j++){
      float4 xv = *(const float4*)&xs[j][i*4];
      acc[j] = fmaf(w[i].x, xv.x, acc[j]);
      acc[j] = fmaf(w[i].y, xv.y, acc[j]);
      acc[j] = fmaf(w[i].z, xv.z, acc[j]);
      acc[j] = fmaf(w[i].w, xv.w, acc[j]);
    }
  }
  float* dst = (t < DI) ? (xin + t) : (z + (t - DI));
  #pragma unroll
  for (int j=0;j<16;j++)
    dst[(size_t)(b*LL + l0 + j)*DI] = acc[j];
}

// ---------------------------------------------------------------- K2: depthwise conv3 (along flat L) + bias + silu
__global__ __launch_bounds__(256) void k2_conv(
    const float* __restrict__ xin, const float* __restrict__ cw,
    const float* __restrict__ cb, float* __restrict__ xc)
{
  int idx = blockIdx.x*256 + threadIdx.x;     // B_*LL*DI = 1,048,576
  int d = idx & (DI-1);
  int l = (idx >> 7) & (LL-1);
  float v = cb[d];
  if (l > 0)      v = fmaf(cw[d*3+0], xin[idx-DI], v);
  v = fmaf(cw[d*3+1], xin[idx], v);
  if (l < LL-1)   v = fmaf(cw[d*3+2], xin[idx+DI], v);
  xc[idx] = siluf_(v);
}

// ---------------------------------------------------------------- K3: zig gather + x_proj + dt_proj + softplus
// per (b,k,32 l's): t36 = xpw[k] @ X_gathered ; delta = softplus(dtw[k]@t36[:4] + bias); B/C = t36[4:36]
__global__ __launch_bounds__(256) void k3_xproj(
    const float* __restrict__ xc, const int* __restrict__ zig,
    const float* __restrict__ xpw, const float* __restrict__ dtw,
    const float* __restrict__ dbias,
    float* __restrict__ delta, float* __restrict__ Bsb, float* __restrict__ Csb)
{
  const int blk = blockIdx.x;              // B_*KD*(LL/32) = 1024
  const int lt = blk & 127;
  const int k  = (blk >> 7) & 3;
  const int b  = blk >> 9;
  const int l0 = lt * 32;
  const int t  = threadIdx.x;
  __shared__ float xt[32*129];             // +1 pad: conflict-free scalar dot reads
  __shared__ float t36[36*33];
  __shared__ int   pj[32];
  if (t < 32) pj[t] = zig[k*LL + l0 + t];
  __syncthreads();
  for (int e = t; e < 32*DI; e += 256){
    int j = e >> 7, dd = e & 127;
    xt[j*129 + dd] = xc[(size_t)(b*LL + pj[j])*DI + dd];
  }
  __syncthreads();
  for (int o = t; o < 36*32; o += 256){
    int c = o >> 5, j = o & 31;
    const float* wr = xpw + (k*36 + c)*DI;
    float acc = 0.f;
    #pragma unroll 8
    for (int i=0;i<DI;i++) acc = fmaf(xt[j*129+i], wr[i], acc);
    t36[c*33 + j] = acc;
  }
  __syncthreads();
  for (int o = t; o < 32*DI; o += 256){
    int j = o >> 7, dd = o & 127;
    float val = dbias[k*DI + dd];
    #pragma unroll
    for (int r=0;r<Rr;r++)
      val = fmaf(t36[r*33 + j], dtw[(k*DI+dd)*Rr + r], val);
    delta[(size_t)((b*KD + k)*LL + l0 + j)*DI + dd] = softplusf_(val);
  }
  for (int o = t; o < 32*32; o += 256){
    int j = o >> 5, m = o & 31;
    float v = t36[(4+m)*33 + j];
    if (m < 16) Bsb[(size_t)((b*KD+k)*LL + l0 + j)*16 + m]      = v;
    else        Csb[(size_t)((b*KD+k)*LL + l0 + j)*16 + (m-16)] = v;
  }
}

// ---------------------------------------------------------------- K4: scan pass 1 (local, per chunk): h_end, S=sum(delta)
__global__ __launch_bounds__(128) void k4_scan1(
    const float* __restrict__ delta, const float* __restrict__ Bsb,
    const float* __restrict__ xc, const int* __restrict__ zig,
    const float* __restrict__ A_logs,
    float* __restrict__ hend, float* __restrict__ Ssum)
{
  const int blk = blockIdx.x;          // (b*KD+k)*NC + c : 512
  const int c = blk & (NC-1);
  const int k = (blk >> 6) & 3;
  const int b = blk >> 8;
  const int d = threadIdx.x;
  float A[Nn], h[Nn];
  #pragma unroll
  for (int n=0;n<Nn;n++){ A[n] = -__expf(A_logs[(k*DI+d)*Nn + n]); h[n] = 0.f; }
  float S = 0.f;
  const int base = (b*KD + k)*LL + c*CS;
  const float* dp = delta + (size_t)base*DI + d;
  const float* Bp = Bsb + (size_t)base*16;
  const int*   zp = zig + k*LL + c*CS;
  for (int s = 0; s < CS; ++s){
    float dl = dp[s*DI];
    int p = zp[s];                              // block-uniform -> scalar load
    float u = xc[(size_t)(b*LL + p)*DI + d];
    float du = dl * u;
    S += dl;
    const float4* B4 = (const float4*)(Bp + s*16);
    float Bv[16];
    #pragma unroll
    for (int q=0;q<4;q++){ float4 bb = B4[q]; Bv[4*q]=bb.x; Bv[4*q+1]=bb.y; Bv[4*q+2]=bb.z; Bv[4*q+3]=bb.w; }
    #pragma unroll
    for (int n=0;n<Nn;n++)
      h[n] = fmaf(__expf(dl * A[n]), h[n], du * Bv[n]);
  }
  float* hp = hend + (size_t)blk*DI*Nn + d*Nn;
  #pragma unroll
  for (int n=0;n<Nn;n++) hp[n] = h[n];
  Ssum[blk*DI + d] = S;
}

// ---------------------------------------------------------------- K5: sequential chunk combine -> h_in per chunk
__global__ __launch_bounds__(256) void k5_combine(
    const float* __restrict__ hend, const float* __restrict__ Ssum,
    const float* __restrict__ A_logs, float* __restrict__ hin)
{
  const int blk = blockIdx.x;          // (b*KD+k)*8 + sub : 64
  const int sub = blk & 7;
  const int bk  = blk >> 3;            // b*KD+k
  const int k   = bk & 3;
  const int e   = sub*256 + threadIdx.x;   // 0..2047 (d*16+n)
  const int d = e >> 4, n = e & 15;
  const float Ae = -__expf(A_logs[(k*DI+d)*Nn + n]);
  float hr = 0.f;
  hin[((size_t)bk*NC + 0)*2048 + e] = 0.f;
  for (int j = 0; j < NC-1; ++j){
    float S  = Ssum[(bk*NC + j)*DI + d];
    float he = hend[((size_t)bk*NC + j)*2048 + e];
    hr = fmaf(__expf(Ae*S), hr, he);          // chunk propagator = exp(A*sum(delta))
    hin[((size_t)bk*NC + j + 1)*2048 + e] = hr;
  }
}

// ---------------------------------------------------------------- K6: scan pass 2: real h_in, emit out_y = y + Ds*u
__global__ __launch_bounds__(128) void k6_scan2(
    const float* __restrict__ delta, const float* __restrict__ Bsb,
    const float* __restrict__ Csb, const float* __restrict__ xc,
    const int* __restrict__ zig, const float* __restrict__ A_logs,
    const float* __restrict__ Dsv, const float* __restrict__ hin,
    float* __restrict__ outy)
{
  const int blk = blockIdx.x;          // 512
  const int c = blk & (NC-1);
  const int k = (blk >> 6) & 3;
  const int b = blk >> 8;
  const int d = threadIdx.x;
  float A[Nn], h[Nn];
  #pragma unroll
  for (int n=0;n<Nn;n++) A[n] = -__expf(A_logs[(k*DI+d)*Nn + n]);
  const float* hp0 = hin + (size_t)blk*2048 + d*Nn;
  #pragma unroll
  for (int n=0;n<Nn;n++) h[n] = hp0[n];
  const float Dv = Dsv[k*DI + d];
  const int base = (b*KD + k)*LL + c*CS;
  const float* dp = delta + (size_t)base*DI + d;
  const float* Bp = Bsb + (size_t)base*16;
  const float* Cp = Csb + (size_t)base*16;
  const int*   zp = zig + k*LL + c*CS;
  for (int s = 0; s < CS; ++s){
    float dl = dp[s*DI];
    int p = zp[s];
    float u = xc[(size_t)(b*LL + p)*DI + d];
    float du = dl * u;
    const float4* B4 = (const float4*)(Bp + s*16);
    const float4* C4 = (const float4*)(Cp + s*16);
    float Bv[16], Cv[16];
    #pragma unroll
    for (int q=0;q<4;q++){
      float4 bb = B4[q]; Bv[4*q]=bb.x; Bv[4*q+1]=bb.y; Bv[4*q+2]=bb.z; Bv[4*q+3]=bb.w;
      float4 cc = C4[q]; Cv[4*q]=cc.x; Cv[4*q+1]=cc.y; Cv[4*q+2]=cc.z; Cv[4*q+3]=cc.w;
    }
    float y = 0.f;
    #pragma unroll
    for (int n=0;n<Nn;n++){
      h[n] = fmaf(__expf(dl * A[n]), h[n], du * Bv[n]);
      y = fmaf(h[n], Cv[n], y);
    }
    outy[(size_t)(base + s)*DI + d] = fmaf(Dv, u, y);
  }
}

// ---------------------------------------------------------------- K7: inverse-zigzag merge (8 paths) + LN + silu(z) gate + out_proj + reverse3d
__global__ __launch_bounds__(128) void k7_out(
    const float* __restrict__ outy, const int* __restrict__ zback,
    const float* __restrict__ z, const float* __restrict__ lnw,
    const float* __restrict__ lnb, const float* __restrict__ opw,
    float* __restrict__ out)
{
  const int bl = blockIdx.x;   // b*LL + l : 8192
  const int b = bl >> 12;
  const int l = bl & (LL-1);
  const int d = threadIdx.x;
  float acc = 0.f;
  #pragma unroll
  for (int i=0;i<8;i++){
    int kk = i & 3;                       // k_sel = [0,1,2,3,0,1,2,3]
    int p = zback[i*LL + l];              // block-uniform
    acc += outy[(size_t)((b*KD + kk)*LL + p)*DI + d];
  }
  // LayerNorm over DI=128 (2 waves)
  float v1 = acc, v2 = acc*acc;
  #pragma unroll
  for (int off=32; off>=1; off>>=1){
    v1 += __shfl_xor(v1, off, 64);
    v2 += __shfl_xor(v2, off, 64);
  }
  __shared__ float r1[2], r2[2];
  __shared__ float yf[DI];
  if ((d & 63) == 0){ r1[d>>6] = v1; r2[d>>6] = v2; }
  __syncthreads();
  float S1 = r1[0]+r1[1], S2 = r2[0]+r2[1];
  float mu = S1 * (1.f/DI);
  float var = S2 * (1.f/DI) - mu*mu;
  float val = (acc - mu) * rsqrtf(var + 1e-5f) * lnw[d] + lnb[d];
  float zv = z[(size_t)bl*DI + d];
  val *= siluf_(zv);
  yf[d] = val;
  __syncthreads();
  if (d < DM){
    const float* wr = opw + d*DI;
    float a2 = 0.f;
    #pragma unroll 8
    for (int i=0;i<DI;i++) a2 = fmaf(yf[i], wr[i], a2);
    int par = (l + b) & 1;
    out[(size_t)bl*DM + (par ? (DM-1-d) : d)] = a2;   // final reverse3d
  }
}

// ---------------------------------------------------------------- launch
extern "C" void kernel_launch(void* const* d_in, const int* in_sizes, int n_in,
                              void* d_out, int out_size, void* d_ws, size_t ws_size,
                              hipStream_t stream)
{
  const float* x     = (const float*)d_in[0];
  const int*   zig   = (const int*)d_in[1];
  const int*   zback = (const int*)d_in[2];
  const float* Wip   = (const float*)d_in[3];
  const float* cw    = (const float*)d_in[4];
  const float* cb    = (const float*)d_in[5];
  const float* xpw   = (const float*)d_in[6];
  const float* dtw   = (const float*)d_in[7];
  const float* dbias = (const float*)d_in[8];
  const float* Alogs = (const float*)d_in[9];
  const float* Dsv   = (const float*)d_in[10];
  const float* lnw   = (const float*)d_in[11];
  const float* lnb   = (const float*)d_in[12];
  const float* opw   = (const float*)d_in[13];
  float* ws = (float*)d_ws;
  // workspace layout (floats)
  float* xin   = ws;                    // 1,048,576
  float* z     = ws + 1048576;          // 1,048,576
  float* xc    = ws + 2097152;          // 1,048,576
  float* delta = ws + 3145728;          // 4,194,304
  float* Bsb   = ws + 7340032;          //   524,288
  float* Csb   = ws + 7864320;          //   524,288
  float* outy  = ws + 8388608;          // 4,194,304
  float* hend  = ws + 12582912;         // 1,048,576
  float* Ssum  = ws + 13631488;         //    65,536
  float* hin   = ws + 13697024;         // 1,048,576  -> total 14,745,600 floats (~59 MB)
  float* out   = (float*)d_out;

  hipLaunchKernelGGL(k1_inproj,  dim3(512),  dim3(256), 0, stream, x, Wip, xin, z);
  hipLaunchKernelGGL(k2_conv,    dim3(4096), dim3(256), 0, stream, xin, cw, cb, xc);
  hipLaunchKernelGGL(k3_xproj,   dim3(1024), dim3(256), 0, stream, xc, zig, xpw, dtw, dbias, delta, Bsb, Csb);
  hipLaunchKernelGGL(k4_scan1,   dim3(512),  dim3(128), 0, stream, delta, Bsb, xc, zig, Alogs, hend, Ssum);
  hipLaunchKernelGGL(k5_combine, dim3(64),   dim3(256), 0, stream, hend, Ssum, Alogs, hin);
  hipLaunchKernelGGL(k6_scan2,   dim3(512),  dim3(128), 0, stream, delta, Bsb, Csb, xc, zig, Alogs, Dsv, hin, outy);
  hipLaunchKernelGGL(k7_out,     dim3(8192), dim3(128), 0, stream, outy, zback, z, lnw, lnb, opw, out);
}